// Round 5
// baseline (147.264 us; speedup 1.0000x reference)
//
#include <hip/hip_runtime.h>
#include <math.h>
#include <float.h>

// Problem constants (match reference)
constexpr int Bn  = 64;
constexpr int ICn = 2;
constexpr int OCn = 32;
constexpr int Kn  = 5;
constexpr int Ln  = 65536;
constexpr float FSc = 50000000.0f;
constexpr int JMAXn = 16;

// Conv tiling: block = one (b, oc, chunk); stages x slab in LDS once,
// writes its 16 KB y-chunk as one linear nt stream.
constexpr int TPB   = 256;
constexpr int CHUNK = 4096;               // y floats per block
constexpr int NCH   = Ln / CHUNK;         // 16 chunks per (b, oc) row
constexpr int ROW   = 4 + CHUNK + 8;      // LDS row: left halo 4, right halo 8 -> 4108
constexpr int GPT   = CHUNK / (TPB * 4);  // float4-groups per thread = 4

typedef float f32x4 __attribute__((ext_vector_type(4)));

// ---------------------------------------------------------------------------
// Kernel 1: per-sample steerable weight generation (unchanged, negligible).
// ---------------------------------------------------------------------------
__global__ __launch_bounds__(64) void wgen_kernel(const int* __restrict__ z,
                                                  const float* __restrict__ s,
                                                  const float* __restrict__ w0,
                                                  float* __restrict__ w) {
    const int b  = blockIdx.x;
    const int oc = threadIdx.x;
    if (oc >= OCn) return;

    float pv[5];
#pragma unroll
    for (int c = 0; c < 5; ++c) {
        float v = s[b * 5 + c];
        if (isnan(v)) v = 0.0f;
        else if (isinf(v)) v = (v > 0.0f) ? FLT_MAX : -FLT_MAX;
        pv[c] = v;
    }
    const float neutral[5] = {0.0f, 1.0f, 1.0f, 0.0f, 0.0f};
#pragma unroll
    for (int c = 0; c < 5; ++c) {
        if (!(z[b * 5 + c] > 0)) pv[c] = neutral[c];
    }
    const float f0    = pv[0];
    const float alpha = pv[1];
    const float rho   = pv[2];
    const float a     = pv[4];

    float nw = rintf(5.0f / fmaxf(alpha, 0.001f));
    int new_W = (int)nw;
    if (new_W < 1) new_W = 1;
    if (new_W > JMAXn) new_W = JMAXn;
    const float nWf = (float)new_W;

    float M[Kn][Kn];
#pragma unroll
    for (int xi = 0; xi < Kn; ++xi)
#pragma unroll
        for (int y = 0; y < Kn; ++y) M[xi][y] = 0.0f;

#pragma unroll
    for (int xi = 0; xi < Kn; ++xi) {
        const float src2 = fmaxf((xi + 0.5f) * nWf / 5.0f - 0.5f, 0.0f);
        const int   j0   = (int)floorf(src2);
        const int   j1   = min(j0 + 1, new_W - 1);
        const float lam2 = src2 - (float)j0;
        const int   jj[2] = {j0, j1};
        const float cf[2] = {1.0f - lam2, lam2};
#pragma unroll
        for (int t = 0; t < 2; ++t) {
            const int   j  = jj[t];
            const float cc = cf[t];
            const float src1 = fmaxf((j + 0.5f) * 5.0f / nWf - 0.5f, 0.0f);
            const int   i0   = (int)floorf(src1);
            const int   i1   = min(i0 + 1, Kn - 1);
            const float lam1 = src1 - (float)i0;
#pragma unroll
            for (int y = 0; y < Kn; ++y) {
                const float e = ((y == i0) ? (1.0f - lam1) : 0.0f) +
                                ((y == i1) ? lam1 : 0.0f);
                M[xi][y] += cc * e;
            }
        }
    }

    const float* w0b = w0 + oc * (ICn * Kn);
    float wI[Kn], wQ[Kn];
#pragma unroll
    for (int xi = 0; xi < Kn; ++xi) {
        float aI = 0.0f, aQ = 0.0f;
#pragma unroll
        for (int y = 0; y < Kn; ++y) {
            aI += M[xi][y] * w0b[y];
            aQ += M[xi][y] * w0b[Kn + y];
        }
        wI[xi] = aI;
        wQ[xi] = aQ;
    }

    const float c2pi = (float)(2.0 * M_PI);
    const float cpi  = (float)M_PI;
#pragma unroll
    for (int n = 0; n < Kn; ++n) {
        const float nf  = (float)n;
        const float ph1 = ((c2pi * f0) * nf) / FSc;
        const float c1 = cosf(ph1), s1 = sinf(ph1);
        float I = wI[n], Q = wQ[n];
        float I2 = I * c1 - Q * s1;
        float Q2 = I * s1 + Q * c1;
        const float t   = nf / FSc;
        const float ph2 = (cpi * a) * (t * t);
        const float c2 = cosf(ph2), s2 = sinf(ph2);
        float I3 = I2 * c2 - Q2 * s2;
        float Q3 = I2 * s2 + Q2 * c2;
        wI[n] = rho * I3;
        wQ[n] = rho * Q3;
    }

    float* wb = w + (b * OCn + oc) * (ICn * Kn);
#pragma unroll
    for (int k = 0; k < Kn; ++k) {
        wb[k]      = wI[k];
        wb[Kn + k] = wQ[k];
    }
}

// ---------------------------------------------------------------------------
// Kernel 2: grouped conv1d. Block = (b, oc, 4096-l chunk), blk linear in y
// (round-3 write topology, proven 4.3 TB/s+). NEW: x slab [cs-4, cs+4104)
// for both ic staged into LDS once (32.9 KB) -> L2 read traffic drops 3x;
// all per-thread windows served from LDS. Stores: nt float4, wave-contiguous.
// ---------------------------------------------------------------------------
__global__ __launch_bounds__(TPB) void conv_kernel(const float* __restrict__ x,
                                                   const float* __restrict__ w,
                                                   float* __restrict__ y) {
    __shared__ float lds[2 * ROW];

    const int blk   = blockIdx.x;
    const int chunk = blk & (NCH - 1);
    const int oc    = (blk >> 4) & (OCn - 1);
    const int b     = blk >> 9;
    const int tid   = (int)threadIdx.x;
    const int cs    = chunk * CHUNK;

    const float* xb = x + (size_t)b * (ICn * Ln);

    // --- stage interior: 2 ic * 4096 floats = 2048 float4, 8 per thread ---
#pragma unroll
    for (int q = 0; q < 8; ++q) {
        const int f4  = q * TPB + tid;        // 0..2047
        const int ic  = f4 >> 10;             // /1024
        const int off = (f4 & 1023) * 4;      // float offset in row
        const float4 v = *reinterpret_cast<const float4*>(xb + ic * Ln + cs + off);
        *reinterpret_cast<float4*>(&lds[ic * ROW + 4 + off]) = v;
    }
    // --- stage halos: 2 ic * (4 left + 8 right) = 24 floats, guarded ---
    if (tid < 24) {
        const int ic = tid / 12;
        const int m  = tid % 12;
        int gl, li;
        if (m < 4) { gl = cs - 4 + m;     li = m; }
        else       { gl = cs + CHUNK + (m - 4); li = 4 + CHUNK + (m - 4); }
        lds[ic * ROW + li] = (gl >= 0 && gl < Ln) ? xb[ic * Ln + gl] : 0.0f;
    }

    // 10 wave-uniform weights for (b, oc)
    const float* wo = w + (size_t)(b * OCn + oc) * (ICn * Kn);
    float wv[ICn * Kn];
#pragma unroll
    for (int i = 0; i < ICn * Kn; ++i) wv[i] = wo[i];

    __syncthreads();

    float* yo = y + ((size_t)(b * OCn + oc)) * Ln + cs;

#pragma unroll 2
    for (int g = 0; g < GPT; ++g) {
        const int ll = g * (TPB * 4) + tid * 4;   // local l of first output
        // window: lds[row + ll + m], m in [0,12)  (maps to x[cs+ll-4+m])
        float xa[12], xc[12];
#pragma unroll
        for (int q = 0; q < 3; ++q) {
            const float4 va = *reinterpret_cast<const float4*>(&lds[ll + 4 * q]);
            const float4 vb = *reinterpret_cast<const float4*>(&lds[ROW + ll + 4 * q]);
            xa[4 * q + 0] = va.x; xa[4 * q + 1] = va.y;
            xa[4 * q + 2] = va.z; xa[4 * q + 3] = va.w;
            xc[4 * q + 0] = vb.x; xc[4 * q + 1] = vb.y;
            xc[4 * q + 2] = vb.z; xc[4 * q + 3] = vb.w;
        }

        float a0 = 0.0f, a1 = 0.0f, a2 = 0.0f, a3 = 0.0f;
#pragma unroll
        for (int k = 0; k < Kn; ++k) {
            const float wA = wv[k];          // ic = 0
            const float wB = wv[Kn + k];     // ic = 1
            a0 = fmaf(wA, xa[k + 2], a0); a0 = fmaf(wB, xc[k + 2], a0);
            a1 = fmaf(wA, xa[k + 3], a1); a1 = fmaf(wB, xc[k + 3], a1);
            a2 = fmaf(wA, xa[k + 4], a2); a2 = fmaf(wB, xc[k + 4], a2);
            a3 = fmaf(wA, xa[k + 5], a3); a3 = fmaf(wB, xc[k + 5], a3);
        }

        f32x4 v = {a0, a1, a2, a3};
        __builtin_nontemporal_store(v, reinterpret_cast<f32x4*>(yo + ll));
    }
}

extern "C" void kernel_launch(void* const* d_in, const int* in_sizes, int n_in,
                              void* d_out, int out_size, void* d_ws, size_t ws_size,
                              hipStream_t stream) {
    const float* x  = (const float*)d_in[0];   // (B, IC, 1, L) f32
    const int*   z  = (const int*)d_in[1];     // (B, 5) i32
    const float* s  = (const float*)d_in[2];   // (B, 5) f32
    const float* w0 = (const float*)d_in[3];   // (OC, IC, 1, K) f32
    float* y = (float*)d_out;                  // (B, OC, 1, L) f32
    float* w = (float*)d_ws;                   // B*OC*IC*K = 20480 floats (80 KB)

    hipLaunchKernelGGL(wgen_kernel, dim3(Bn), dim3(64), 0, stream, z, s, w0, w);
    hipLaunchKernelGGL(conv_kernel, dim3(Bn * OCn * NCH), dim3(TPB), 0, stream, x, w, y);
}

// Round 6
// 113.324 us; speedup vs baseline: 1.2995x; 1.2995x over previous
//
#include <hip/hip_runtime.h>
#include <math.h>
#include <float.h>

// Problem constants (match reference)
constexpr int Bn  = 64;
constexpr int ICn = 2;
constexpr int OCn = 32;
constexpr int Kn  = 5;
constexpr int Ln  = 65536;
constexpr float FSc = 50000000.0f;
constexpr int JMAXn = 16;

// Conv tiling: block = (b, oc-group of 4, 16384-l chunk). 2048 blocks.
constexpr int TPB   = 256;
constexpr int CHUNK = 16384;             // l span per block
constexpr int NCH   = Ln / CHUNK;        // 4
constexpr int OCG   = 4;                 // oc per block
constexpr int NG    = OCn / OCG;         // 8 groups
constexpr int ITERS = CHUNK / (TPB * 4); // 16

typedef float f32x4 __attribute__((ext_vector_type(4)));

// ---------------------------------------------------------------------------
// Kernel 1: per-sample steerable weight generation (unchanged, negligible).
// ---------------------------------------------------------------------------
__global__ __launch_bounds__(64) void wgen_kernel(const int* __restrict__ z,
                                                  const float* __restrict__ s,
                                                  const float* __restrict__ w0,
                                                  float* __restrict__ w) {
    const int b  = blockIdx.x;
    const int oc = threadIdx.x;
    if (oc >= OCn) return;

    float pv[5];
#pragma unroll
    for (int c = 0; c < 5; ++c) {
        float v = s[b * 5 + c];
        if (isnan(v)) v = 0.0f;
        else if (isinf(v)) v = (v > 0.0f) ? FLT_MAX : -FLT_MAX;
        pv[c] = v;
    }
    const float neutral[5] = {0.0f, 1.0f, 1.0f, 0.0f, 0.0f};
#pragma unroll
    for (int c = 0; c < 5; ++c) {
        if (!(z[b * 5 + c] > 0)) pv[c] = neutral[c];
    }
    const float f0    = pv[0];
    const float alpha = pv[1];
    const float rho   = pv[2];
    const float a     = pv[4];

    float nw = rintf(5.0f / fmaxf(alpha, 0.001f));
    int new_W = (int)nw;
    if (new_W < 1) new_W = 1;
    if (new_W > JMAXn) new_W = JMAXn;
    const float nWf = (float)new_W;

    float M[Kn][Kn];
#pragma unroll
    for (int xi = 0; xi < Kn; ++xi)
#pragma unroll
        for (int y = 0; y < Kn; ++y) M[xi][y] = 0.0f;

#pragma unroll
    for (int xi = 0; xi < Kn; ++xi) {
        const float src2 = fmaxf((xi + 0.5f) * nWf / 5.0f - 0.5f, 0.0f);
        const int   j0   = (int)floorf(src2);
        const int   j1   = min(j0 + 1, new_W - 1);
        const float lam2 = src2 - (float)j0;
        const int   jj[2] = {j0, j1};
        const float cf[2] = {1.0f - lam2, lam2};
#pragma unroll
        for (int t = 0; t < 2; ++t) {
            const int   j  = jj[t];
            const float cc = cf[t];
            const float src1 = fmaxf((j + 0.5f) * 5.0f / nWf - 0.5f, 0.0f);
            const int   i0   = (int)floorf(src1);
            const int   i1   = min(i0 + 1, Kn - 1);
            const float lam1 = src1 - (float)i0;
#pragma unroll
            for (int y = 0; y < Kn; ++y) {
                const float e = ((y == i0) ? (1.0f - lam1) : 0.0f) +
                                ((y == i1) ? lam1 : 0.0f);
                M[xi][y] += cc * e;
            }
        }
    }

    const float* w0b = w0 + oc * (ICn * Kn);
    float wI[Kn], wQ[Kn];
#pragma unroll
    for (int xi = 0; xi < Kn; ++xi) {
        float aI = 0.0f, aQ = 0.0f;
#pragma unroll
        for (int y = 0; y < Kn; ++y) {
            aI += M[xi][y] * w0b[y];
            aQ += M[xi][y] * w0b[Kn + y];
        }
        wI[xi] = aI;
        wQ[xi] = aQ;
    }

    const float c2pi = (float)(2.0 * M_PI);
    const float cpi  = (float)M_PI;
#pragma unroll
    for (int n = 0; n < Kn; ++n) {
        const float nf  = (float)n;
        const float ph1 = ((c2pi * f0) * nf) / FSc;
        const float c1 = cosf(ph1), s1 = sinf(ph1);
        float I = wI[n], Q = wQ[n];
        float I2 = I * c1 - Q * s1;
        float Q2 = I * s1 + Q * c1;
        const float t   = nf / FSc;
        const float ph2 = (cpi * a) * (t * t);
        const float c2 = cosf(ph2), s2 = sinf(ph2);
        float I3 = I2 * c2 - Q2 * s2;
        float Q3 = I2 * s2 + Q2 * c2;
        wI[n] = rho * I3;
        wQ[n] = rho * Q3;
    }

    float* wb = w + (b * OCn + oc) * (ICn * Kn);
#pragma unroll
    for (int k = 0; k < Kn; ++k) {
        wb[k]      = wI[k];
        wb[Kn + k] = wQ[k];
    }
}

// ---------------------------------------------------------------------------
// Kernel 2: grouped conv1d. R3's proven topology (block linear in y, nt
// float4 stores, x window in regs) + OC-GROUP=4: each window feeds 4 oc,
// so each load-wait period issues a BURST of 4 contiguous stores and the
// load/store instruction ratio drops 4x (vmcnt FIFO decoupling).
// ---------------------------------------------------------------------------
__global__ __launch_bounds__(TPB) void conv_kernel(const float* __restrict__ x,
                                                   const float* __restrict__ w,
                                                   float* __restrict__ y) {
    const int blk   = blockIdx.x;
    const int chunk = blk & (NCH - 1);
    const int g     = (blk >> 2) & (NG - 1);
    const int b     = blk >> 5;
    const int oc0   = g * OCG;

    // 40 wave-uniform weights (scalar-cached): wv[j][i] for oc0+j
    const float* wbase = w + (size_t)(b * OCn + oc0) * (ICn * Kn);
    float wv[OCG][ICn * Kn];
#pragma unroll
    for (int j = 0; j < OCG; ++j)
#pragma unroll
        for (int i = 0; i < ICn * Kn; ++i) wv[j][i] = wbase[j * (ICn * Kn) + i];

    const float* x0 = x + (size_t)b * (ICn * Ln);
    const float* x1 = x0 + Ln;
    float* yg = y + ((size_t)(b * OCn + oc0)) * Ln + chunk * CHUNK;

    const int l0base = chunk * CHUNK + (int)threadIdx.x * 4;

#pragma unroll 2
    for (int it = 0; it < ITERS; ++it) {
        const int l0 = l0base + it * (TPB * 4);
        // window x[l0-4 .. l0+8): 12 floats per ic; used x[l0-2 .. l0+6)
        float xa[12], xc[12];
        if (l0 >= 4 && l0 + 8 <= Ln) {
#pragma unroll
            for (int q = 0; q < 3; ++q) {
                const float4 va = *reinterpret_cast<const float4*>(x0 + l0 - 4 + 4 * q);
                const float4 vb = *reinterpret_cast<const float4*>(x1 + l0 - 4 + 4 * q);
                xa[4 * q + 0] = va.x; xa[4 * q + 1] = va.y;
                xa[4 * q + 2] = va.z; xa[4 * q + 3] = va.w;
                xc[4 * q + 0] = vb.x; xc[4 * q + 1] = vb.y;
                xc[4 * q + 2] = vb.z; xc[4 * q + 3] = vb.w;
            }
        } else {
#pragma unroll
            for (int m = 0; m < 12; ++m) {
                const int gl = l0 - 4 + m;
                const bool ok = (gl >= 0 && gl < Ln);
                xa[m] = ok ? x0[gl] : 0.0f;
                xc[m] = ok ? x1[gl] : 0.0f;
            }
        }

        // 4 oc x 4 l accumulators from the shared window
        float acc[OCG][4];
#pragma unroll
        for (int j = 0; j < OCG; ++j) {
            float a0 = 0.0f, a1 = 0.0f, a2 = 0.0f, a3 = 0.0f;
#pragma unroll
            for (int k = 0; k < Kn; ++k) {
                const float wA = wv[j][k];        // ic = 0
                const float wB = wv[j][Kn + k];   // ic = 1
                a0 = fmaf(wA, xa[k + 2], a0); a0 = fmaf(wB, xc[k + 2], a0);
                a1 = fmaf(wA, xa[k + 3], a1); a1 = fmaf(wB, xc[k + 3], a1);
                a2 = fmaf(wA, xa[k + 4], a2); a2 = fmaf(wB, xc[k + 4], a2);
                a3 = fmaf(wA, xa[k + 5], a3); a3 = fmaf(wB, xc[k + 5], a3);
            }
            acc[j][0] = a0; acc[j][1] = a1; acc[j][2] = a2; acc[j][3] = a3;
        }

        // burst of 4 contiguous nt stores (each: 64 lanes x 16 B = 1 KB line-run)
        const int off = it * (TPB * 4) + (int)threadIdx.x * 4;
#pragma unroll
        for (int j = 0; j < OCG; ++j) {
            f32x4 v = {acc[j][0], acc[j][1], acc[j][2], acc[j][3]};
            __builtin_nontemporal_store(
                v, reinterpret_cast<f32x4*>(yg + (size_t)j * Ln + off));
        }
    }
}

extern "C" void kernel_launch(void* const* d_in, const int* in_sizes, int n_in,
                              void* d_out, int out_size, void* d_ws, size_t ws_size,
                              hipStream_t stream) {
    const float* x  = (const float*)d_in[0];   // (B, IC, 1, L) f32
    const int*   z  = (const int*)d_in[1];     // (B, 5) i32
    const float* s  = (const float*)d_in[2];   // (B, 5) f32
    const float* w0 = (const float*)d_in[3];   // (OC, IC, 1, K) f32
    float* y = (float*)d_out;                  // (B, OC, 1, L) f32
    float* w = (float*)d_ws;                   // B*OC*IC*K = 20480 floats (80 KB)

    hipLaunchKernelGGL(wgen_kernel, dim3(Bn), dim3(64), 0, stream, z, s, w0, w);
    hipLaunchKernelGGL(conv_kernel, dim3(Bn * NG * NCH), dim3(TPB), 0, stream, x, w, y);
}